// Round 4
// baseline (55.221 us; speedup 1.0000x reference)
//
#include <hip/hip_runtime.h>
#include <cstdint>
#include <cstddef>

#define B 4096
#define S 200
#define V 33
#define T 50
#define EPSV 1e-08
#define NLL_BLOCKS 64
#define ROWS_PER_NLL_BLOCK (B / NLL_BLOCKS)   // 64

// ws layout:
// [0]      double ll_part[B]       32 KiB
// [32768]  unsigned cnt_part[B]    16 KiB
// [49152]  double nll_part[64]     512 B
// Every slot is unconditionally written by its owning block each call:
// no memset node needed, poison/replay-safe.

using f4  = __attribute__((ext_vector_type(4))) float;
using f4u = __attribute__((aligned(4))) f4;          // 4B-aligned float4 view

__device__ __forceinline__ bool is_nan_bits(float x) {
    uint32_t u = __float_as_uint(x);
    return (u & 0x7F800000u) == 0x7F800000u && (u & 0x007FFFFFu) != 0u;
}

__global__ __launch_bounds__(256)
void fused_kernel(const float* __restrict__ long_pred,
                  const float* __restrict__ surv_pred,
                  const float* __restrict__ data,
                  const uint32_t* __restrict__ event_words,
                  const float* __restrict__ event_time,
                  const float* __restrict__ time_range,
                  double* __restrict__ ll_part,
                  unsigned int* __restrict__ cnt_part,
                  double* __restrict__ nll_part) {
    const int tid = threadIdx.x;
    const int blk = blockIdx.x;

    if (blk < B) {
        // ------------- longitudinal loss: one block per batch row -----------
        const int b = blk;
        const float* __restrict__ dbase  = data      + (size_t)b * (S * V);
        const float* __restrict__ lpbase = long_pred + (size_t)b * (S * (V - 1));

        // one parallel probe round: validity is a prefix, count == length
        int valid = 0;
        if (tid < S) valid = !is_nan_bits(dbase[(size_t)tid * V + 1]);
        const int len = __syncthreads_count(valid);

        // flat float4 sweep over the lp region [0, (len-1)*32).
        // lp vec k covers floats j=4k..4k+3 of row srow=k>>3 (cols 4(k&7)..+3
        // of long_pred), matching data floats at j + srow + 34 (cols 1..32 of
        // row srow+1). lp loads 16B-aligned; data loads 4B-aligned dwordx4.
        const int nvec = (len - 1) * 8;
        float acc = 0.0f;
        for (int k0 = tid; k0 < nvec; k0 += 4 * 256) {
            f4 lpv[4], dv[4];
            #pragma unroll
            for (int u = 0; u < 4; ++u) {
                int k  = k0 + u * 256;
                int kc = k < nvec ? k : (nvec - 1);     // clamp: safe address
                int j  = kc * 4;
                int sr = kc >> 3;
                lpv[u] = *reinterpret_cast<const f4*>(lpbase + j);
                dv[u]  = *reinterpret_cast<const f4u*>(dbase + j + sr + 34);
            }
            #pragma unroll
            for (int u = 0; u < 4; ++u) {
                if (k0 + u * 256 < nvec) {
                    f4 df = lpv[u] - dv[u];
                    acc = fmaf(df[0], df[0], acc);
                    acc = fmaf(df[1], df[1], acc);
                    acc = fmaf(df[2], df[2], acc);
                    acc = fmaf(df[3], df[3], acc);
                }
            }
        }

        for (int off = 32; off > 0; off >>= 1) acc += __shfl_down(acc, off);
        __shared__ float s_sum[4];
        int wib  = tid >> 6;
        int lane = tid & 63;
        if (lane == 0) s_sum[wib] = acc;
        __syncthreads();
        if (tid == 0) {
            ll_part[b] = (double)s_sum[0] + (double)s_sum[1]
                       + (double)s_sum[2] + (double)s_sum[3];
            cnt_part[b] = (unsigned)(len - 1);
        }
    } else {
        // ------------- survival NLL: 64 batch rows per block -----------------
        const int nb = blk - B;

        // detect event storage layout (redundant per block; 4 KiB, L2-hit)
        __shared__ int s_gt1, s_oddnz;
        if (tid == 0) { s_gt1 = 0; s_oddnz = 0; }
        __syncthreads();
        int gt1 = 0, oddnz = 0;
        for (int i = tid; i < B / 4; i += 256) {   // exactly B bytes: safe
            uint32_t w = event_words[i];
            if (w > 1u) gt1 = 1;
            if ((i & 1) && w != 0u) oddnz = 1;
        }
        if (gt1)   atomicOr(&s_gt1, 1);
        if (oddnz) atomicOr(&s_oddnz, 1);
        __syncthreads();
        const int mode = s_gt1 ? 1 : (s_oddnz ? 0 : 2);  // 1=u8, 0=i32, 2=i64

        const int wib  = tid >> 6;
        const int lane = tid & 63;
        double nsum = 0.0;

        for (int r = 0; r < ROWS_PER_NLL_BLOCK / 4; ++r) {
            int b = nb * ROWS_PER_NLL_BLOCK + r * 4 + wib;
            float sv = (lane < T) ? surv_pred[b * T + lane] : 0.0f;
            float tr = (lane < T) ? time_range[lane] : 0.0f;
            float et = event_time[b];

            // searchsorted(time_range, et, 'right') - 1
            unsigned long long bal = __ballot(lane < T && tr <= et);
            int idx = (int)__popcll(bal) - 1;

            // tail = sum_{t >= idx+1} surv_pred[b,t]
            float tval = (lane < T && lane >= idx + 1) ? sv : 0.0f;
            for (int off = 32; off > 0; off >>= 1) tval += __shfl_down(tval, off);

            int   idx_c  = idx < 0 ? 0 : idx;
            float at_idx = __shfl(sv, idx_c);

            bool ev;
            if (mode == 1)      ev = ((const unsigned char*)event_words)[b] != 0;
            else if (mode == 2) ev = ((const int*)event_words)[2 * b] != 0;
            else                ev = ((const int*)event_words)[b] != 0;

            if (lane == 0) {
                float f = ev ? at_idx : ((idx + 1 < T) ? tval : 0.0f);
                if (f == 0.0f) f = (float)EPSV;
                nsum += -log((double)f);
            }
        }

        __shared__ double s_n[4];
        if (lane == 0) s_n[wib] = nsum;
        __syncthreads();
        if (tid == 0) nll_part[nb] = s_n[0] + s_n[1] + s_n[2] + s_n[3];
    }
}

__global__ __launch_bounds__(256)
void finalize_kernel(const double* __restrict__ ll_part,
                     const unsigned* __restrict__ cnt_part,
                     const double* __restrict__ nll_part,
                     float* __restrict__ out) {
    const int tid = threadIdx.x;
    double             ls = 0.0;
    unsigned long long cs = 0;
    double             ns = 0.0;
    for (int i = tid; i < B; i += 256) { ls += ll_part[i]; cs += cnt_part[i]; }
    if (tid < NLL_BLOCKS) ns = nll_part[tid];

    for (int off = 32; off > 0; off >>= 1) {
        ls += __shfl_down(ls, off);
        cs += __shfl_down(cs, off);
        ns += __shfl_down(ns, off);
    }
    __shared__ double             sl[4], sn[4];
    __shared__ unsigned long long sc[4];
    int wib = tid >> 6, lane = tid & 63;
    if (lane == 0) { sl[wib] = ls; sc[wib] = cs; sn[wib] = ns; }
    __syncthreads();
    if (tid == 0) {
        double L = 0.0, N = 0.0;
        unsigned long long C = 0;
        for (int i = 0; i < 4; ++i) { L += sl[i]; C += sc[i]; N += sn[i]; }
        double denom = (double)C * (double)(V - 1);
        out[0] = (float)(N / (double)B + L / denom);
    }
}

extern "C" void kernel_launch(void* const* d_in, const int* in_sizes, int n_in,
                              void* d_out, int out_size, void* d_ws, size_t ws_size,
                              hipStream_t stream) {
    const float* long_pred  = (const float*)d_in[0];
    const float* surv_pred  = (const float*)d_in[1];
    const float* data       = (const float*)d_in[2];
    const void*  event      = d_in[3];
    const float* event_time = (const float*)d_in[4];
    const float* time_range = (const float*)d_in[5];
    float* out = (float*)d_out;

    double*   ll_part  = (double*)d_ws;
    unsigned* cnt_part = (unsigned*)((char*)d_ws + 32768);
    double*   nll_part = (double*)((char*)d_ws + 49152);

    fused_kernel<<<B + NLL_BLOCKS, 256, 0, stream>>>(
        long_pred, surv_pred, data, (const uint32_t*)event, event_time,
        time_range, ll_part, cnt_part, nll_part);
    finalize_kernel<<<1, 256, 0, stream>>>(ll_part, cnt_part, nll_part, out);
}

// Round 5
// 37.342 us; speedup vs baseline: 1.4788x; 1.4788x over previous
//
#include <hip/hip_runtime.h>
#include <cstdint>
#include <cstddef>

#define B 4096
#define S 200
#define V 33
#define T 50
#define EPSV 1e-08

#define SWEEP_BLOCKS 1024   // 4 batch-rows each
#define NLLB 1024           // 4 batch-rows each (one wave per row)

// ws layout:
// [0]      double ll_part[SWEEP_BLOCKS]   8 KiB
// [8192]   double nll_part[NLLB]          8 KiB
// [16384]  int    lengths[B]             16 KiB
// [32768]  int    mode
// Every slot is unconditionally written each call: poison/replay-safe.

using f4  = __attribute__((ext_vector_type(4))) float;
using f4u = __attribute__((aligned(4))) f4;          // 4B-aligned float4 view

__device__ __forceinline__ bool is_nan_bits(float x) {
    uint32_t u = __float_as_uint(x);
    return (u & 0x7F800000u) == 0x7F800000u && (u & 0x007FFFFFu) != 0u;
}

// ---- kernel A: lengths via 2-round wave ballot + event-mode detect ----------
__global__ __launch_bounds__(256)
void lengths_kernel(const float* __restrict__ data,
                    const uint32_t* __restrict__ event_words,
                    int* __restrict__ lengths, int* __restrict__ mode_p) {
    const int lane = threadIdx.x & 63;
    const int b    = (int)((blockIdx.x * blockDim.x + threadIdx.x) >> 6);
    if (b < B) {
        const float* __restrict__ dbase = data + (size_t)b * (S * V);
        // coarse: lane l<50 probes row 4l+3 (col 1). prefix validity =>
        // popc == len>>2
        int v1 = 0;
        if (lane < 50) v1 = !is_nan_bits(dbase[(size_t)(4 * lane + 3) * V + 1]);
        int c1 = (int)__popcll(__ballot(v1 != 0));
        int r  = 4 * c1;
        // refine: rows r..r+2 (row r+3 known invalid)
        int v2 = 0;
        if (lane < 3 && r + lane < S)
            v2 = !is_nan_bits(dbase[(size_t)(r + lane) * V + 1]);
        int d = (int)__popcll(__ballot(v2 != 0));
        if (lane == 0) lengths[b] = r + d;
    }
    // event storage detect: block 0, wave 0 (scan exactly B bytes: safe)
    if (blockIdx.x == 0 && threadIdx.x < 64) {
        int gt1 = 0, oddnz = 0;
        for (int i = lane; i < B / 4; i += 64) {
            uint32_t w = event_words[i];
            if (w > 1u) gt1 = 1;
            if ((i & 1) && w != 0u) oddnz = 1;
        }
        unsigned long long bg = __ballot(gt1 != 0);
        unsigned long long bo = __ballot(oddnz != 0);
        if (lane == 0) *mode_p = bg ? 1 : (bo ? 0 : 2);  // 1=u8, 0=i32, 2=i64
    }
}

// ---- clamped flat float4 sweep batch ----------------------------------------
// lp vec k covers floats j=4k..4k+3 (row k>>3); matching data floats at
// j + (k>>3) + 34 (cols 1..32 of row (k>>3)+1).
template <int D>
__device__ __forceinline__ void sweep_batch(const float* __restrict__ lpbase,
                                            const float* __restrict__ dbase,
                                            int k0, int nvec, float& acc) {
    f4 lpv[D], dv[D];
    #pragma unroll
    for (int u = 0; u < D; ++u) {
        int k  = k0 + u * 256;
        int kc = k < nvec ? k : (nvec - 1);
        int j  = kc * 4;
        int sr = kc >> 3;
        lpv[u] = *reinterpret_cast<const f4*>(lpbase + j);
        dv[u]  = *reinterpret_cast<const f4u*>(dbase + j + sr + 34);
    }
    #pragma unroll
    for (int u = 0; u < D; ++u) {
        if (k0 + u * 256 < nvec) {
            f4 df = lpv[u] - dv[u];
            acc = fmaf(df[0], df[0], acc);
            acc = fmaf(df[1], df[1], acc);
            acc = fmaf(df[2], df[2], acc);
            acc = fmaf(df[3], df[3], acc);
        }
    }
}

// ---- kernel B: barrier-free sweep + wide NLL --------------------------------
__global__ __launch_bounds__(256, 4)
void main_kernel(const float* __restrict__ long_pred,
                 const float* __restrict__ surv_pred,
                 const float* __restrict__ data,
                 const uint32_t* __restrict__ event_words,
                 const float* __restrict__ event_time,
                 const float* __restrict__ time_range,
                 const int* __restrict__ lengths,
                 const int* __restrict__ mode_p,
                 double* __restrict__ ll_part,
                 double* __restrict__ nll_part) {
    const int tid = threadIdx.x;
    const int blk = blockIdx.x;

    if (blk < SWEEP_BLOCKS) {
        const int b0 = blk * 4;
        float acc = 0.0f;
        #pragma unroll
        for (int bb = 0; bb < 4; ++bb) {
            const int b = b0 + bb;
            const float* __restrict__ dbase  = data      + (size_t)b * (S * V);
            const float* __restrict__ lpbase = long_pred + (size_t)b * (S * (V - 1));
            const int nvec = (lengths[b] - 1) * 8;       // <= 1592
            sweep_batch<4>(lpbase, dbase, tid, nvec, acc);          // k < 1024
            if (nvec > 1024)
                sweep_batch<3>(lpbase, dbase, tid + 1024, nvec, acc); // k < 1792
        }
        for (int off = 32; off > 0; off >>= 1) acc += __shfl_down(acc, off);
        __shared__ float s_sum[4];
        const int wib = tid >> 6, lane = tid & 63;
        if (lane == 0) s_sum[wib] = acc;
        __syncthreads();
        if (tid == 0)
            ll_part[blk] = (double)s_sum[0] + (double)s_sum[1]
                         + (double)s_sum[2] + (double)s_sum[3];
    } else {
        // one wave per batch row: single dependent round
        const int wib  = tid >> 6;
        const int lane = tid & 63;
        const int b    = (blk - SWEEP_BLOCKS) * 4 + wib;
        const int mode = *mode_p;

        float sv = (lane < T) ? surv_pred[b * T + lane] : 0.0f;
        float tr = (lane < T) ? time_range[lane] : 0.0f;
        float et = event_time[b];

        // searchsorted(time_range, et, 'right') - 1
        unsigned long long bal = __ballot(lane < T && tr <= et);
        int idx = (int)__popcll(bal) - 1;

        // tail = sum_{t >= idx+1} surv_pred[b,t]
        float tval = (lane < T && lane >= idx + 1) ? sv : 0.0f;
        for (int off = 32; off > 0; off >>= 1) tval += __shfl_down(tval, off);

        int   idx_c  = idx < 0 ? 0 : idx;
        float at_idx = __shfl(sv, idx_c);

        bool ev;
        if (mode == 1)      ev = ((const unsigned char*)event_words)[b] != 0;
        else if (mode == 2) ev = ((const int*)event_words)[2 * b] != 0;
        else                ev = ((const int*)event_words)[b] != 0;

        __shared__ double s_n[4];
        if (lane == 0) {
            float f = ev ? at_idx : ((idx + 1 < T) ? tval : 0.0f);
            if (f == 0.0f) f = (float)EPSV;
            s_n[wib] = -(double)logf(f);
        }
        __syncthreads();
        if (tid == 0)
            nll_part[blk - SWEEP_BLOCKS] = s_n[0] + s_n[1] + s_n[2] + s_n[3];
    }
}

// ---- kernel C: finalize ------------------------------------------------------
__global__ __launch_bounds__(256)
void finalize_kernel(const double* __restrict__ ll_part,
                     const double* __restrict__ nll_part,
                     const int* __restrict__ lengths,
                     float* __restrict__ out) {
    const int tid = threadIdx.x;
    double ls = 0.0, ns = 0.0;
    long long cs = 0;
    for (int i = tid; i < SWEEP_BLOCKS; i += 256) ls += ll_part[i];
    for (int i = tid; i < NLLB; i += 256)         ns += nll_part[i];
    for (int i = tid; i < B; i += 256)            cs += lengths[i];

    for (int off = 32; off > 0; off >>= 1) {
        ls += __shfl_down(ls, off);
        ns += __shfl_down(ns, off);
        cs += __shfl_down(cs, off);
    }
    __shared__ double    sl[4], sn[4];
    __shared__ long long sc[4];
    const int wib = tid >> 6, lane = tid & 63;
    if (lane == 0) { sl[wib] = ls; sn[wib] = ns; sc[wib] = cs; }
    __syncthreads();
    if (tid == 0) {
        double L = 0.0, N = 0.0;
        long long C = 0;
        for (int i = 0; i < 4; ++i) { L += sl[i]; N += sn[i]; C += sc[i]; }
        C -= B;                                   // sum(len-1)
        double denom = (double)C * (double)(V - 1);
        out[0] = (float)(N / (double)B + L / denom);
    }
}

extern "C" void kernel_launch(void* const* d_in, const int* in_sizes, int n_in,
                              void* d_out, int out_size, void* d_ws, size_t ws_size,
                              hipStream_t stream) {
    const float* long_pred  = (const float*)d_in[0];
    const float* surv_pred  = (const float*)d_in[1];
    const float* data       = (const float*)d_in[2];
    const void*  event      = d_in[3];
    const float* event_time = (const float*)d_in[4];
    const float* time_range = (const float*)d_in[5];
    float* out = (float*)d_out;

    double* ll_part  = (double*)d_ws;
    double* nll_part = (double*)((char*)d_ws + 8192);
    int*    lengths  = (int*)((char*)d_ws + 16384);
    int*    mode_p   = (int*)((char*)d_ws + 32768);

    lengths_kernel<<<B / 4, 256, 0, stream>>>(data, (const uint32_t*)event,
                                              lengths, mode_p);
    main_kernel<<<SWEEP_BLOCKS + NLLB, 256, 0, stream>>>(
        long_pred, surv_pred, data, (const uint32_t*)event, event_time,
        time_range, lengths, mode_p, ll_part, nll_part);
    finalize_kernel<<<1, 256, 0, stream>>>(ll_part, nll_part, lengths, out);
}

// Round 7
// 31.295 us; speedup vs baseline: 1.7645x; 1.1932x over previous
//
#include <hip/hip_runtime.h>
#include <cstdint>
#include <cstddef>

#define B 4096
#define S 200
#define V 33
#define T 50
#define EPSV 1e-08

#define NLLB 1024                 // NLL blocks (4 batch rows each), blk < NLLB
#define GRID (NLLB + B)           // sweep block for b = blk - NLLB

// ws layout:
// [0]      double ll_part[B]     32 KiB
// [32768]  int    lenm1[B]       16 KiB
// [49152]  double nll_part[NLLB]  8 KiB
// Every slot is unconditionally written by its owning block each call:
// no memset node, poison/replay-safe, fully deterministic.

using f4  = __attribute__((ext_vector_type(4))) float;
using f4u = __attribute__((aligned(4))) f4;          // 4B-aligned float4 view

__device__ __forceinline__ bool is_nan_bits(float x) {
    uint32_t u = __float_as_uint(x);
    return (u & 0x7F800000u) == 0x7F800000u && (u & 0x007FFFFFu) != 0u;
}

// Clamped flat float4 sweep batch with NaN masking.
// lp vec k covers floats j=4k..4k+3 (lp row k>>3); matching data floats at
// j + (k>>3) + 34 (cols 1..32 of row (k>>3)+1). Rows past len are all-NaN:
// zero their diffs; count valid rows via the (k&7)==0 vec's first element.
template <int D>
__device__ __forceinline__ void sweep_batch(const float* __restrict__ lpbase,
                                            const float* __restrict__ dbase,
                                            int k0, int nvec,
                                            float& acc, int& cnt) {
    f4 lpv[D], dv[D];
    #pragma unroll
    for (int u = 0; u < D; ++u) {
        int k  = k0 + u * 256;
        int kc = k < nvec ? k : (nvec - 1);
        int j  = kc * 4;
        int sr = kc >> 3;
        lpv[u] = *reinterpret_cast<const f4*>(lpbase + j);
        dv[u]  = *reinterpret_cast<const f4u*>(dbase + j + sr + 34);
    }
    #pragma unroll
    for (int u = 0; u < D; ++u) {
        int k = k0 + u * 256;
        if (k < nvec) {
            #pragma unroll
            for (int i = 0; i < 4; ++i) {
                float de = dv[u][i];
                float df = lpv[u][i] - de;
                if (is_nan_bits(de)) df = 0.0f;
                acc = fmaf(df, df, acc);
            }
            if ((k & 7) == 0 && !is_nan_bits(dv[u][0])) cnt++;
        }
    }
}

__global__ __launch_bounds__(256, 4)
void fused_kernel(const float* __restrict__ long_pred,
                  const float* __restrict__ surv_pred,
                  const float* __restrict__ data,
                  const uint32_t* __restrict__ event_words,
                  const float* __restrict__ event_time,
                  const float* __restrict__ time_range,
                  double* __restrict__ ll_part,
                  int* __restrict__ lenm1,
                  double* __restrict__ nll_part) {
    const int tid  = threadIdx.x;
    const int blk  = blockIdx.x;
    const int wib  = tid >> 6;
    const int lane = tid & 63;

    if (blk < NLLB) {
        // ---------------- survival NLL: 4 batch rows per block ---------------
        // event storage detect (scan exactly B bytes: safe in all layouts)
        __shared__ int s_gt1, s_oddnz;
        if (tid == 0) { s_gt1 = 0; s_oddnz = 0; }
        __syncthreads();
        int gt1 = 0, oddnz = 0;
        for (int i = tid; i < B / 4; i += 256) {
            uint32_t w = event_words[i];
            if (w > 1u) gt1 = 1;
            if ((i & 1) && w != 0u) oddnz = 1;
        }
        if (gt1)   atomicOr(&s_gt1, 1);
        if (oddnz) atomicOr(&s_oddnz, 1);
        __syncthreads();
        const int mode = s_gt1 ? 1 : (s_oddnz ? 0 : 2);  // 1=u8, 0=i32, 2=i64

        const int b = blk * 4 + wib;
        float sv = (lane < T) ? surv_pred[b * T + lane] : 0.0f;
        float tr = (lane < T) ? time_range[lane] : 0.0f;
        float et = event_time[b];

        // searchsorted(time_range, et, 'right') - 1
        unsigned long long bal = __ballot(lane < T && tr <= et);
        int idx = (int)__popcll(bal) - 1;

        // tail = sum_{t >= idx+1} surv_pred[b,t]
        float tval = (lane < T && lane >= idx + 1) ? sv : 0.0f;
        for (int off = 32; off > 0; off >>= 1) tval += __shfl_down(tval, off);

        int   idx_c  = idx < 0 ? 0 : idx;
        float at_idx = __shfl(sv, idx_c);

        bool ev;
        if (mode == 1)      ev = ((const unsigned char*)event_words)[b] != 0;
        else if (mode == 2) ev = ((const int*)event_words)[2 * b] != 0;
        else                ev = ((const int*)event_words)[b] != 0;

        __shared__ double s_n[4];
        if (lane == 0) {
            float f = ev ? at_idx : ((idx + 1 < T) ? tval : 0.0f);
            if (f == 0.0f) f = (float)EPSV;
            s_n[wib] = -(double)logf(f);
        }
        __syncthreads();
        if (tid == 0) nll_part[blk] = s_n[0] + s_n[1] + s_n[2] + s_n[3];
    } else {
        // ---------------- longitudinal sweep: one batch row per block --------
        const int b = blk - NLLB;
        const float* __restrict__ dbase  = data      + (size_t)b * (S * V);
        const float* __restrict__ lpbase = long_pred + (size_t)b * (S * (V - 1));

        // one probe round: threads 0..49 test row 4t+3 col 1 (prefix validity)
        int valid = 0;
        if (tid < 50) valid = !is_nan_bits(dbase[(size_t)(4 * tid + 3) * V + 1]);
        const int c1 = __syncthreads_count(valid);       // = #valid probes
        const int bound_rows = min(4 * c1 + 2, S - 1);   // >= len-1, <= len+2
        const int nvec = bound_rows * 8;                 // <= 1592

        float acc = 0.0f;
        int   cnt = 0;
        sweep_batch<4>(lpbase, dbase, tid, nvec, acc, cnt);            // k<1024
        if (nvec > 1024)
            sweep_batch<3>(lpbase, dbase, tid + 1024, nvec, acc, cnt); // k<1792

        for (int off = 32; off > 0; off >>= 1) {
            acc += __shfl_down(acc, off);
            cnt += __shfl_down(cnt, off);
        }
        __shared__ float s_red[4];
        __shared__ int   s_cnt[4];
        if (lane == 0) { s_red[wib] = acc; s_cnt[wib] = cnt; }
        __syncthreads();
        if (tid == 0) {
            ll_part[b] = (double)s_red[0] + (double)s_red[1]
                       + (double)s_red[2] + (double)s_red[3];
            lenm1[b]   = s_cnt[0] + s_cnt[1] + s_cnt[2] + s_cnt[3];
        }
    }
}

__global__ __launch_bounds__(256)
void finalize_kernel(const double* __restrict__ ll_part,
                     const int* __restrict__ lenm1,
                     const double* __restrict__ nll_part,
                     float* __restrict__ out) {
    const int tid = threadIdx.x;
    double ls = 0.0, ns = 0.0;
    long long cs = 0;
    for (int i = tid; i < B; i += 256)    { ls += ll_part[i]; cs += lenm1[i]; }
    for (int i = tid; i < NLLB; i += 256) ns += nll_part[i];

    for (int off = 32; off > 0; off >>= 1) {
        ls += __shfl_down(ls, off);
        ns += __shfl_down(ns, off);
        cs += __shfl_down(cs, off);
    }
    __shared__ double    sl[4], sn[4];
    __shared__ long long sc[4];
    const int wib = tid >> 6, lane = tid & 63;
    if (lane == 0) { sl[wib] = ls; sn[wib] = ns; sc[wib] = cs; }
    __syncthreads();
    if (tid == 0) {
        double L = 0.0, N = 0.0;
        long long C = 0;
        for (int i = 0; i < 4; ++i) { L += sl[i]; N += sn[i]; C += sc[i]; }
        double denom = (double)C * (double)(V - 1);
        out[0] = (float)(N / (double)B + L / denom);
    }
}

extern "C" void kernel_launch(void* const* d_in, const int* in_sizes, int n_in,
                              void* d_out, int out_size, void* d_ws, size_t ws_size,
                              hipStream_t stream) {
    const float* long_pred  = (const float*)d_in[0];
    const float* surv_pred  = (const float*)d_in[1];
    const float* data       = (const float*)d_in[2];
    const void*  event      = d_in[3];
    const float* event_time = (const float*)d_in[4];
    const float* time_range = (const float*)d_in[5];
    float* out = (float*)d_out;

    double* ll_part  = (double*)d_ws;
    int*    lenm1    = (int*)((char*)d_ws + 32768);
    double* nll_part = (double*)((char*)d_ws + 49152);

    fused_kernel<<<GRID, 256, 0, stream>>>(
        long_pred, surv_pred, data, (const uint32_t*)event, event_time,
        time_range, ll_part, lenm1, nll_part);
    finalize_kernel<<<1, 256, 0, stream>>>(ll_part, lenm1, nll_part, out);
}